// Round 2
// baseline (2418.915 us; speedup 1.0000x reference)
//
#include <hip/hip_runtime.h>
#include <hip/hip_bf16.h>
#include <math.h>

#define SEQ   2048
#define BATCH 2
#define DM    1024
#define NH    16
#define DH    64
#define TOK   (BATCH*SEQ)   // 4096
#define BHN   (BATCH*NH)    // 32

typedef __hip_bfloat16 bf16;

__device__ __forceinline__ float b2f(bf16 x) { return __bfloat162float(x); }

// Dual-dtype load/store: fl==1 -> buffer holds fp32, fl==0 -> bf16.
__device__ __forceinline__ float ldf(const void* p, size_t i, int fl) {
    return fl ? ((const float*)p)[i] : b2f(((const bf16*)p)[i]);
}
__device__ __forceinline__ void stf(void* p, size_t i, int fl, float v) {
    if (fl) ((float*)p)[i] = v;
    else    ((bf16*)p)[i]  = __float2bfloat16(v);
}

// ---------------------------------------------------------------------------
// Detect whether float tensors are stored as fp32 or bf16.
// Real bf16 activations: |v| <= ~10. fp32 bits misread as bf16: random
// exponents -> values >> 1e4 / NaN among the first 2048 half-words, w.p. ~1.
// ---------------------------------------------------------------------------
__global__ void detect_dtype(const void* __restrict__ x, int* __restrict__ flag)
{
    __shared__ int s_bad;
    if (threadIdx.x == 0) s_bad = 0;
    __syncthreads();
    const bf16* p = (const bf16*)x;
    int bad = 0;
    for (int i = threadIdx.x; i < 2048; i += 256) {
        float v = b2f(p[i]);
        if (!(fabsf(v) <= 1e4f)) bad = 1;   // also true for NaN
    }
    if (bad) atomicOr(&s_bad, 1);
    __syncthreads();
    if (threadIdx.x == 0) *flag = s_bad;
}

// ---------------------------------------------------------------------------
// Qw/Kw/Vw (bf16, B,H,S,Dh) = X(4096x1024) @ W(1024x1024) + bias, permuted.
// 64x64 tile, 4x4 per thread, fp32 accumulate, VALU only.
// ---------------------------------------------------------------------------
__global__ __launch_bounds__(256)
void gemm_qkv(const void* __restrict__ X, const void* __restrict__ W,
              const void* __restrict__ bias, bf16* __restrict__ out,
              const int* __restrict__ flag)
{
    const int fl = *flag;
    __shared__ float As[16][65];   // [k][m]
    __shared__ float Bs[16][65];   // [k][n]
    const int tid = threadIdx.x;
    const int tx = tid & 15, ty = tid >> 4;
    const int n0 = blockIdx.x * 64;
    const int m0 = blockIdx.y * 64;
    float acc[4][4] = {};
    for (int k0 = 0; k0 < DM; k0 += 16) {
        const int c = tid & 15, r = tid >> 4;          // A: 64 rows x 16 k
        #pragma unroll
        for (int p = 0; p < 4; ++p)
            As[c][r + p*16] = ldf(X, (size_t)(m0 + r + p*16)*DM + k0 + c, fl);
        const int nn = tid & 63, kk0 = tid >> 6;       // B: 16 k x 64 n
        #pragma unroll
        for (int p = 0; p < 4; ++p)
            Bs[kk0 + p*4][nn] = ldf(W, (size_t)(k0 + kk0 + p*4)*DM + n0 + nn, fl);
        __syncthreads();
        #pragma unroll
        for (int kk = 0; kk < 16; ++kk) {
            float a[4], b[4];
            #pragma unroll
            for (int i = 0; i < 4; ++i) a[i] = As[kk][ty*4+i];
            #pragma unroll
            for (int j = 0; j < 4; ++j) b[j] = Bs[kk][tx*4+j];
            #pragma unroll
            for (int i = 0; i < 4; ++i)
                #pragma unroll
                for (int j = 0; j < 4; ++j)
                    acc[i][j] += a[i]*b[j];
        }
        __syncthreads();
    }
    #pragma unroll
    for (int i = 0; i < 4; ++i) {
        const int t  = m0 + ty*4 + i;
        const int b_ = t >> 11, s = t & (SEQ-1);
        #pragma unroll
        for (int j = 0; j < 4; ++j) {
            const int n = n0 + tx*4 + j;
            const int h = n >> 6, d = n & 63;
            out[(((size_t)(b_*NH + h))*SEQ + s)*DH + d] =
                __float2bfloat16(acc[i][j] + ldf(bias, n, fl));
        }
    }
}

// ---------------------------------------------------------------------------
// Raw scores into d_out's attn region: Sc[bh][q][k] = (Q.K)/8, dual dtype.
// ---------------------------------------------------------------------------
__global__ __launch_bounds__(256)
void qk_gemm(const bf16* __restrict__ Q, const bf16* __restrict__ K,
             void* __restrict__ d_out_base, const int* __restrict__ flag)
{
    const int fl = *flag;
    const size_t esz = fl ? 4 : 2;
    char* attnw = (char*)d_out_base + (size_t)TOK * DM * esz;

    __shared__ float Qs[64][65];
    __shared__ float Ks[64][65];
    const int tid = threadIdx.x;
    const int tx = tid & 15, ty = tid >> 4;
    const int k0 = blockIdx.x * 64;
    const int q0 = blockIdx.y * 64;
    const size_t bh = blockIdx.z;
    const bf16* Qb = Q + bh * SEQ * DH;
    const bf16* Kb = K + bh * SEQ * DH;
    const int d = tid & 63, r0 = tid >> 6;
    #pragma unroll
    for (int p = 0; p < 16; ++p) {
        const int r = r0 + p*4;
        Qs[r][d] = b2f(Qb[(size_t)(q0 + r)*DH + d]);
        Ks[r][d] = b2f(Kb[(size_t)(k0 + r)*DH + d]);
    }
    __syncthreads();
    float acc[4][4] = {};
    #pragma unroll 8
    for (int dd = 0; dd < 64; ++dd) {
        float a[4], b[4];
        #pragma unroll
        for (int i = 0; i < 4; ++i) a[i] = Qs[ty*4+i][dd];
        #pragma unroll
        for (int j = 0; j < 4; ++j) b[j] = Ks[tx*4+j][dd];
        #pragma unroll
        for (int i = 0; i < 4; ++i)
            #pragma unroll
            for (int j = 0; j < 4; ++j)
                acc[i][j] += a[i]*b[j];
    }
    void* Srow = attnw + bh * SEQ * SEQ * esz;
    #pragma unroll
    for (int i = 0; i < 4; ++i)
        #pragma unroll
        for (int j = 0; j < 4; ++j)
            stf(Srow, (size_t)(q0 + ty*4 + i)*SEQ + k0 + tx*4 + j, fl,
                acc[i][j] * 0.125f);
}

// ---------------------------------------------------------------------------
// In-place masked softmax over each score row (dual dtype). 1 block / row.
// ---------------------------------------------------------------------------
__global__ __launch_bounds__(256)
void softmax_rows(void* __restrict__ d_out_base, const int* __restrict__ mask,
                  const int* __restrict__ flag)
{
    const int fl = *flag;
    const size_t esz = fl ? 4 : 2;
    char* attnw = (char*)d_out_base + (size_t)TOK * DM * esz;

    const int row = blockIdx.x;          // bh*SEQ + q
    const int bh  = row >> 11;
    const int b_  = bh >> 4;
    void* prow = attnw + (size_t)row * SEQ * esz;
    const int tid = threadIdx.x;
    __shared__ float red[4];
    float vals[8];
    float m = -INFINITY;
    #pragma unroll
    for (int i = 0; i < 8; ++i) {
        const int c = tid + i*256;
        float s = ldf(prow, c, fl);
        if (mask[b_*SEQ + c] == 0) s = -INFINITY;
        vals[i] = s;
        m = fmaxf(m, s);
    }
    #pragma unroll
    for (int off = 32; off > 0; off >>= 1)
        m = fmaxf(m, __shfl_down(m, off));
    if ((tid & 63) == 0) red[tid >> 6] = m;
    __syncthreads();
    m = fmaxf(fmaxf(red[0], red[1]), fmaxf(red[2], red[3]));
    __syncthreads();                       // red reuse
    float l = 0.f;
    #pragma unroll
    for (int i = 0; i < 8; ++i) { vals[i] = __expf(vals[i] - m); l += vals[i]; }
    #pragma unroll
    for (int off = 32; off > 0; off >>= 1)
        l += __shfl_down(l, off);
    if ((tid & 63) == 0) red[tid >> 6] = l;
    __syncthreads();
    const float inv = 1.f / (red[0] + red[1] + red[2] + red[3]);
    #pragma unroll
    for (int i = 0; i < 8; ++i)
        stf(prow, tid + i*256, fl, vals[i] * inv);
}

// ---------------------------------------------------------------------------
// AO (bf16, B,S,H*Dh) = P(bh,S,S dual) @ V(bh,S,Dh bf16). 64x64 tile.
// ---------------------------------------------------------------------------
__global__ __launch_bounds__(256)
void pv_gemm(void* __restrict__ d_out_base, const bf16* __restrict__ V,
             bf16* __restrict__ AO, const int* __restrict__ flag)
{
    const int fl = *flag;
    const size_t esz = fl ? 4 : 2;
    char* attnw = (char*)d_out_base + (size_t)TOK * DM * esz;

    __shared__ float As[16][65];   // [k][m]
    __shared__ float Bs[16][65];   // [k][n]
    const int tid = threadIdx.x;
    const int tx = tid & 15, ty = tid >> 4;
    const int m0 = blockIdx.x * 64;
    const int bh = blockIdx.y;
    const int b_ = bh >> 4, h = bh & 15;
    const void* Pb = attnw + (size_t)bh * SEQ * SEQ * esz;
    const bf16* Vb = V + (size_t)bh * SEQ * DH;
    float acc[4][4] = {};
    for (int k0 = 0; k0 < SEQ; k0 += 16) {
        const int c = tid & 15, r = tid >> 4;
        #pragma unroll
        for (int p = 0; p < 4; ++p)
            As[c][r + p*16] = ldf(Pb, (size_t)(m0 + r + p*16)*SEQ + k0 + c, fl);
        const int nn = tid & 63, kk0 = tid >> 6;
        #pragma unroll
        for (int p = 0; p < 4; ++p)
            Bs[kk0 + p*4][nn] = b2f(Vb[(size_t)(k0 + kk0 + p*4)*DH + nn]);
        __syncthreads();
        #pragma unroll
        for (int kk = 0; kk < 16; ++kk) {
            float a[4], b[4];
            #pragma unroll
            for (int i = 0; i < 4; ++i) a[i] = As[kk][ty*4+i];
            #pragma unroll
            for (int j = 0; j < 4; ++j) b[j] = Bs[kk][tx*4+j];
            #pragma unroll
            for (int i = 0; i < 4; ++i)
                #pragma unroll
                for (int j = 0; j < 4; ++j)
                    acc[i][j] += a[i]*b[j];
        }
        __syncthreads();
    }
    #pragma unroll
    for (int i = 0; i < 4; ++i) {
        const int q = m0 + ty*4 + i;
        #pragma unroll
        for (int j = 0; j < 4; ++j)
            AO[((size_t)(b_*SEQ + q))*DM + h*DH + tx*4 + j] =
                __float2bfloat16(acc[i][j]);
    }
}

// ---------------------------------------------------------------------------
// out0 (dual) = AO(4096x1024 bf16) @ Wo + bo
// ---------------------------------------------------------------------------
__global__ __launch_bounds__(256)
void gemm_out(const bf16* __restrict__ A, const void* __restrict__ W,
              const void* __restrict__ bias, void* __restrict__ d_out_base,
              const int* __restrict__ flag)
{
    const int fl = *flag;
    __shared__ float As[16][65];
    __shared__ float Bs[16][65];
    const int tid = threadIdx.x;
    const int tx = tid & 15, ty = tid >> 4;
    const int n0 = blockIdx.x * 64;
    const int m0 = blockIdx.y * 64;
    float acc[4][4] = {};
    for (int k0 = 0; k0 < DM; k0 += 16) {
        const int c = tid & 15, r = tid >> 4;
        #pragma unroll
        for (int p = 0; p < 4; ++p)
            As[c][r + p*16] = b2f(A[(size_t)(m0 + r + p*16)*DM + k0 + c]);
        const int nn = tid & 63, kk0 = tid >> 6;
        #pragma unroll
        for (int p = 0; p < 4; ++p)
            Bs[kk0 + p*4][nn] = ldf(W, (size_t)(k0 + kk0 + p*4)*DM + n0 + nn, fl);
        __syncthreads();
        #pragma unroll
        for (int kk = 0; kk < 16; ++kk) {
            float a[4], b[4];
            #pragma unroll
            for (int i = 0; i < 4; ++i) a[i] = As[kk][ty*4+i];
            #pragma unroll
            for (int j = 0; j < 4; ++j) b[j] = Bs[kk][tx*4+j];
            #pragma unroll
            for (int i = 0; i < 4; ++i)
                #pragma unroll
                for (int j = 0; j < 4; ++j)
                    acc[i][j] += a[i]*b[j];
        }
        __syncthreads();
    }
    #pragma unroll
    for (int i = 0; i < 4; ++i) {
        const int t = m0 + ty*4 + i;
        #pragma unroll
        for (int j = 0; j < 4; ++j) {
            const int n = n0 + tx*4 + j;
            stf(d_out_base, (size_t)t*DM + n, fl, acc[i][j] + ldf(bias, n, fl));
        }
    }
}

// ---------------------------------------------------------------------------
extern "C" void kernel_launch(void* const* d_in, const int* in_sizes, int n_in,
                              void* d_out, int out_size, void* d_ws, size_t ws_size,
                              hipStream_t stream)
{
    const void* x    = d_in[0];
    const int*  mask = (const int*)d_in[1];
    const void* Wq   = d_in[2];
    const void* bq   = d_in[3];
    const void* Wk   = d_in[4];
    const void* bk   = d_in[5];
    const void* Wv   = d_in[6];
    const void* bv   = d_in[7];
    const void* Wo   = d_in[8];
    const void* bo   = d_in[9];

    // ws layout: [flag int | pad to 256B | Qw 8MB | Kw 8MB | Vw 8MB]
    // AO (bf16, 8MB) reuses Qw's region (Q dead after qk_gemm). Peak: 24MB+256B.
    int*  flag = (int*)d_ws;
    const size_t qkv_elems = (size_t)BHN * SEQ * DH;  // 4,194,304
    bf16* Qw = (bf16*)((char*)d_ws + 256);
    bf16* Kw = Qw + qkv_elems;
    bf16* Vw = Kw + qkv_elems;
    bf16* AO = Qw;                                    // reuse

    dim3 blk(256);
    dim3 gProj(DM/64, TOK/64);                        // 16 x 64

    detect_dtype<<<1, blk, 0, stream>>>(x, flag);

    gemm_qkv<<<gProj, blk, 0, stream>>>(x, Wq, bq, Qw, flag);
    gemm_qkv<<<gProj, blk, 0, stream>>>(x, Wk, bk, Kw, flag);
    gemm_qkv<<<gProj, blk, 0, stream>>>(x, Wv, bv, Vw, flag);

    qk_gemm<<<dim3(SEQ/64, SEQ/64, BHN), blk, 0, stream>>>(Qw, Kw, d_out, flag);

    softmax_rows<<<dim3(BHN*SEQ), blk, 0, stream>>>(d_out, mask, flag);

    pv_gemm<<<dim3(SEQ/64, BHN), blk, 0, stream>>>(d_out, Vw, AO, flag);

    gemm_out<<<gProj, blk, 0, stream>>>(AO, Wo, bo, d_out, flag);
}